// Round 3
// baseline (289.384 us; speedup 1.0000x reference)
//
#include <hip/hip_runtime.h>
#include <math.h>

#define Bn 32
#define Cn 256
#define Hn 64
#define Wn 64
#define HWn 4096
#define CRn 16   // C / R

__device__ __forceinline__ float sigmoidf_(float v) { return 1.0f / (1.0f + __expf(-v)); }

// ---------------- Kernel 1: per-(b,c) mean & max over HW ----------------
__global__ __launch_bounds__(256) void k_chanstats(const float* __restrict__ x,
                                                   float* __restrict__ avg,
                                                   float* __restrict__ mx) {
    int bc = blockIdx.x;                      // 0 .. B*C-1
    const float4* xv = (const float4*)(x + (size_t)bc * HWn);
    int t = threadIdx.x;
    float s = 0.0f, m = -INFINITY;
#pragma unroll
    for (int j = 0; j < 4; ++j) {             // 4096 floats = 1024 float4 / 256 thr
        float4 v = xv[t + j * 256];
        s += v.x + v.y + v.z + v.w;
        m = fmaxf(m, fmaxf(fmaxf(v.x, v.y), fmaxf(v.z, v.w)));
    }
#pragma unroll
    for (int off = 32; off > 0; off >>= 1) {
        s += __shfl_down(s, off);
        m = fmaxf(m, __shfl_down(m, off));
    }
    __shared__ float ss[4], sm[4];
    int wave = t >> 6, lane = t & 63;
    if (lane == 0) { ss[wave] = s; sm[wave] = m; }
    __syncthreads();
    if (t == 0) {
        s = ss[0] + ss[1] + ss[2] + ss[3];
        m = fmaxf(fmaxf(sm[0], sm[1]), fmaxf(sm[2], sm[3]));
        avg[bc] = s * (1.0f / HWn);
        mx[bc]  = m;
    }
}

// ---------------- Kernel 2: shared MLP + sigmoid -> ch_att ----------------
// All 256 threads active: 32 dot products (16 avg-path + 16 max-path), each
// split into 8 chunks of 32 MACs; LDS reduce; then 256 threads do the 16-MAC
// output layer. Lane map d = t&31 keeps the sv[] broadcast conflict-free.
__global__ __launch_bounds__(256) void k_mlp(const float* __restrict__ avg,
                                             const float* __restrict__ mx,
                                             const float* __restrict__ w1,
                                             const float* __restrict__ w2,
                                             float* __restrict__ ch_att) {
    int b = blockIdx.x;
    int t = threadIdx.x;
    __shared__ float sv[2][Cn];
    __shared__ float part[32][8];
    __shared__ float h[32];
    sv[0][t] = avg[b * Cn + t];
    sv[1][t] = mx[b * Cn + t];
    __syncthreads();
    int d  = t & 31;          // dot index: d<16 -> avg-path h[d], else max-path
    int ch = t >> 5;          // chunk 0..7
    int r  = d & 15;
    const float* v = sv[d >> 4];
    const float* wrow = w1 + r * Cn + ch * 32;
    float acc = 0.0f;
#pragma unroll
    for (int c = 0; c < 32; ++c) acc += v[ch * 32 + c] * wrow[c];
    part[d][ch] = acc;
    __syncthreads();
    if (t < 32) {
        float a = 0.0f;
#pragma unroll
        for (int k = 0; k < 8; ++k) a += part[t][k];
        h[t] = fmaxf(a, 0.0f);                // relu
    }
    __syncthreads();
    float acc2 = 0.0f;
#pragma unroll
    for (int rr = 0; rr < CRn; ++rr) acc2 += (h[rr] + h[CRn + rr]) * w2[t * CRn + rr];
    ch_att[b * Cn + t] = sigmoidf_(acc2);
}

// ---------------- Kernel 3: per-(b,hw) mean & max over C of x*ch_att ----------------
// 2048 blocks (8/CU): block = 16 f4-lanes x 16 c-groups covering a 64-float hw
// segment. Each thread reduces 16 channels (c = i*16+cg: conflict-free satt
// broadcast), then in-wave shfl reduce across the 4 c-groups per wave, then a
// tiny 2 KB LDS combine across the 4 waves.
__global__ __launch_bounds__(256) void k_spstats(const float* __restrict__ x,
                                                 const float* __restrict__ ch_att,
                                                 float* __restrict__ avg_sp,
                                                 float* __restrict__ max_sp) {
    int blk = blockIdx.x;            // Bn*64
    int b = blk >> 6;
    int seg = blk & 63;              // 64-float segment of the HW plane
    int t = threadIdx.x;
    int f4 = t & 15;
    int cg = t >> 4;                 // 16 channel groups

    __shared__ float satt[Cn];
    satt[t] = ch_att[b * Cn + t];
    __syncthreads();

    const float* xb = x + ((size_t)b * Cn) * HWn + seg * 64;
    float4 s = {0.f, 0.f, 0.f, 0.f};
    float4 m = {-INFINITY, -INFINITY, -INFINITY, -INFINITY};
#pragma unroll
    for (int i = 0; i < 16; ++i) {
        int c = (i << 4) + cg;
        float4 v = ((const float4*)(xb + (size_t)c * HWn))[f4];
        float a = satt[c];
        v.x *= a; v.y *= a; v.z *= a; v.w *= a;
        s.x += v.x; s.y += v.y; s.z += v.z; s.w += v.w;
        m.x = fmaxf(m.x, v.x); m.y = fmaxf(m.y, v.y);
        m.z = fmaxf(m.z, v.z); m.w = fmaxf(m.w, v.w);
    }
    // reduce across the 4 c-groups within each wave (lane stride 16)
#pragma unroll
    for (int off = 32; off >= 16; off >>= 1) {
        s.x += __shfl_down(s.x, off); s.y += __shfl_down(s.y, off);
        s.z += __shfl_down(s.z, off); s.w += __shfl_down(s.w, off);
        m.x = fmaxf(m.x, __shfl_down(m.x, off));
        m.y = fmaxf(m.y, __shfl_down(m.y, off));
        m.z = fmaxf(m.z, __shfl_down(m.z, off));
        m.w = fmaxf(m.w, __shfl_down(m.w, off));
    }
    __shared__ float4 ps[4][16], pm[4][16];
    int wave = t >> 6, lane = t & 63;
    if (lane < 16) { ps[wave][lane] = s; pm[wave][lane] = m; }
    __syncthreads();
    if (t < 16) {
        s = ps[0][t]; m = pm[0][t];
#pragma unroll
        for (int g = 1; g < 4; ++g) {
            float4 os = ps[g][t], om = pm[g][t];
            s.x += os.x; s.y += os.y; s.z += os.z; s.w += os.w;
            m.x = fmaxf(m.x, om.x); m.y = fmaxf(m.y, om.y);
            m.z = fmaxf(m.z, om.z); m.w = fmaxf(m.w, om.w);
        }
        const float inv = 1.0f / Cn;
        float4 av = {s.x * inv, s.y * inv, s.z * inv, s.w * inv};
        ((float4*)(avg_sp + b * HWn + seg * 64))[t] = av;
        ((float4*)(max_sp + b * HWn + seg * 64))[t] = m;
    }
}

// ---------------- Kernel 4: fused 7x7 SAME conv + sigmoid + final multiply ----------
// 1024 blocks (4/CU): block = (b, 2 rows). Loads the 8-row sp halo into LDS
// (zero-padded), computes att for its 128 px, then streams all 256 channels of
// the 2-row tile: out = x * ch_att * att with float4 stores.
__global__ __launch_bounds__(256) void k_convfinal(const float* __restrict__ x,
                                                   const float* __restrict__ ch_att,
                                                   const float* __restrict__ avg_sp,
                                                   const float* __restrict__ max_sp,
                                                   const float* __restrict__ w_sp,
                                                   float* __restrict__ out) {
    int blk = blockIdx.x;            // Bn*32
    int b = blk >> 5;
    int y0 = (blk & 31) << 1;        // 2 rows per block
    int t = threadIdx.x;

    __shared__ float ca[Cn];
    __shared__ float wk[98];
    __shared__ float ha[8][64];      // avg_sp halo rows y0-3 .. y0+4 (zero-padded)
    __shared__ float hm[8][64];
    __shared__ float att2[128];      // att for the 2 output rows

    ca[t] = ch_att[b * Cn + t];
    if (t < 98) wk[t] = w_sp[t];
    const float* ab = avg_sp + b * HWn;
    const float* mb = max_sp + b * HWn;
#pragma unroll
    for (int k = 0; k < 4; ++k) {
        int idx = k * 256 + t;        // 0..1023
        int mapi = idx >> 9;          // 0: avg map, 1: max map
        int r = (idx >> 6) & 7;       // halo row 0..7
        int col = idx & 63;
        int y = y0 - 3 + r;
        float v = 0.0f;
        if (y >= 0 && y < Hn) v = (mapi == 0 ? ab : mb)[y * Wn + col];
        if (mapi == 0) ha[r][col] = v; else hm[r][col] = v;
    }
    __syncthreads();

    if (t < 128) {
        int row = t >> 6;             // 0..1
        int col = t & 63;
        float acc = 0.0f;
#pragma unroll
        for (int ky = 0; ky < 7; ++ky) {
            int hr = row + ky;        // halo row index (0..7)
#pragma unroll
            for (int kx = 0; kx < 7; ++kx) {
                int xc = col + kx - 3;
                if (xc < 0 || xc >= Wn) continue;
                acc += ha[hr][xc] * wk[ky * 7 + kx] + hm[hr][xc] * wk[49 + ky * 7 + kx];
            }
        }
        att2[t] = sigmoidf_(acc);
    }
    __syncthreads();

    int f4 = t & 31;                  // 32 float4 = 128 px tile
    int cg = t >> 5;                  // 8 groups x 32 channels
    float4 a4 = ((const float4*)att2)[f4];
    size_t base = ((size_t)b * Cn) * HWn + (size_t)y0 * Wn;  // float offset at c=0
    const float* xb = x + base;
    float* ob = out + base;
#pragma unroll 4
    for (int i = 0; i < 32; ++i) {
        int c = (i << 3) + cg;        // conflict-free ca[] broadcast
        size_t off = (size_t)c * HWn;
        float4 v = ((const float4*)(xb + off))[f4];
        float sfac = ca[c];
        float4 rv;
        rv.x = v.x * sfac * a4.x;
        rv.y = v.y * sfac * a4.y;
        rv.z = v.z * sfac * a4.z;
        rv.w = v.w * sfac * a4.w;
        ((float4*)(ob + off))[f4] = rv;
    }
}

extern "C" void kernel_launch(void* const* d_in, const int* in_sizes, int n_in,
                              void* d_out, int out_size, void* d_ws, size_t ws_size,
                              hipStream_t stream) {
    const float* x    = (const float*)d_in[0];   // [32,256,64,64]
    const float* w1   = (const float*)d_in[1];   // [16,256]
    const float* w2   = (const float*)d_in[2];   // [256,16]
    const float* w_sp = (const float*)d_in[3];   // [1,2,7,7]
    float* out = (float*)d_out;

    float* ws = (float*)d_ws;
    float* avg    = ws;                      // B*C
    float* mx     = avg + Bn * Cn;
    float* ch_att = mx + Bn * Cn;
    float* avg_sp = ch_att + Bn * Cn;        // B*HW
    float* max_sp = avg_sp + Bn * HWn;

    k_chanstats<<<Bn * Cn, 256, 0, stream>>>(x, avg, mx);
    k_mlp<<<Bn, 256, 0, stream>>>(avg, mx, w1, w2, ch_att);
    k_spstats<<<Bn * 64, 256, 0, stream>>>(x, ch_att, avg_sp, max_sp);
    k_convfinal<<<Bn * 32, 256, 0, stream>>>(x, ch_att, avg_sp, max_sp, w_sp, out);
}

// Round 4
// 277.420 us; speedup vs baseline: 1.0431x; 1.0431x over previous
//
#include <hip/hip_runtime.h>
#include <math.h>

#define Bn 32
#define Cn 256
#define Hn 64
#define Wn 64
#define HWn 4096
#define CRn 16   // C / R

__device__ __forceinline__ float sigmoidf_(float v) { return 1.0f / (1.0f + __expf(-v)); }

// ---------------- Kernel 1: per-(b,c) mean & max over HW ----------------
__global__ __launch_bounds__(256) void k_chanstats(const float* __restrict__ x,
                                                   float* __restrict__ avg,
                                                   float* __restrict__ mx) {
    int bc = blockIdx.x;                      // 0 .. B*C-1
    const float4* xv = (const float4*)(x + (size_t)bc * HWn);
    int t = threadIdx.x;
    float s = 0.0f, m = -INFINITY;
#pragma unroll
    for (int j = 0; j < 4; ++j) {             // 4096 floats = 1024 float4 / 256 thr
        float4 v = xv[t + j * 256];
        s += v.x + v.y + v.z + v.w;
        m = fmaxf(m, fmaxf(fmaxf(v.x, v.y), fmaxf(v.z, v.w)));
    }
#pragma unroll
    for (int off = 32; off > 0; off >>= 1) {
        s += __shfl_down(s, off);
        m = fmaxf(m, __shfl_down(m, off));
    }
    __shared__ float ss[4], sm[4];
    int wave = t >> 6, lane = t & 63;
    if (lane == 0) { ss[wave] = s; sm[wave] = m; }
    __syncthreads();
    if (t == 0) {
        s = ss[0] + ss[1] + ss[2] + ss[3];
        m = fmaxf(fmaxf(sm[0], sm[1]), fmaxf(sm[2], sm[3]));
        avg[bc] = s * (1.0f / HWn);
        mx[bc]  = m;
    }
}

// ---------------- Kernel 2: MLP (inline, redundant per block) + spatial stats ------
// 2048 blocks (8/CU). Each block first recomputes the shared-MLP channel attention
// for its batch b (8K MACs, ~0.2us, avoids a separate 32-block dispatch), then
// computes per-(b,hw) mean/max over C of x*ch_att for its 64-float hw segment.
// seg==0 blocks also store ch_att for the conv+final kernel.
__global__ __launch_bounds__(256) void k_spstats(const float* __restrict__ x,
                                                 const float* __restrict__ avg,
                                                 const float* __restrict__ mx,
                                                 const float* __restrict__ w1,
                                                 const float* __restrict__ w2,
                                                 float* __restrict__ ch_att,
                                                 float* __restrict__ avg_sp,
                                                 float* __restrict__ max_sp) {
    int blk = blockIdx.x;            // Bn*64
    int b = blk >> 6;
    int seg = blk & 63;              // 64-float segment of the HW plane
    int t = threadIdx.x;

    // ---- inline MLP -> satt[256] ----
    __shared__ float sv[2][Cn];
    __shared__ float part[32][8];
    __shared__ float h[32];
    __shared__ float satt[Cn];
    sv[0][t] = avg[b * Cn + t];
    sv[1][t] = mx[b * Cn + t];
    __syncthreads();
    {
        int d  = t & 31;              // dot index: d<16 -> avg-path, else max-path
        int chk = t >> 5;             // chunk 0..7
        int r  = d & 15;
        const float* v = sv[d >> 4];
        const float* wrow = w1 + r * Cn + chk * 32;
        float acc = 0.0f;
#pragma unroll
        for (int c = 0; c < 32; ++c) acc += v[chk * 32 + c] * wrow[c];
        part[d][chk] = acc;
    }
    __syncthreads();
    if (t < 32) {
        float a = 0.0f;
#pragma unroll
        for (int k = 0; k < 8; ++k) a += part[t][k];
        h[t] = fmaxf(a, 0.0f);        // relu
    }
    __syncthreads();
    {
        float a2 = 0.0f;
#pragma unroll
        for (int rr = 0; rr < CRn; ++rr) a2 += (h[rr] + h[CRn + rr]) * w2[t * CRn + rr];
        float catt = sigmoidf_(a2);
        satt[t] = catt;
        if (seg == 0) ch_att[b * Cn + t] = catt;
    }
    __syncthreads();

    // ---- spatial stats over C ----
    int f4 = t & 15;
    int cg = t >> 4;                 // 16 channel groups
    const float* xb = x + ((size_t)b * Cn) * HWn + seg * 64;
    float4 s = {0.f, 0.f, 0.f, 0.f};
    float4 m = {-INFINITY, -INFINITY, -INFINITY, -INFINITY};
#pragma unroll
    for (int i = 0; i < 16; ++i) {
        int c = (i << 4) + cg;
        float4 v = ((const float4*)(xb + (size_t)c * HWn))[f4];
        float a = satt[c];
        v.x *= a; v.y *= a; v.z *= a; v.w *= a;
        s.x += v.x; s.y += v.y; s.z += v.z; s.w += v.w;
        m.x = fmaxf(m.x, v.x); m.y = fmaxf(m.y, v.y);
        m.z = fmaxf(m.z, v.z); m.w = fmaxf(m.w, v.w);
    }
    // reduce across the 4 c-groups within each wave (lane stride 16)
#pragma unroll
    for (int off = 32; off >= 16; off >>= 1) {
        s.x += __shfl_down(s.x, off); s.y += __shfl_down(s.y, off);
        s.z += __shfl_down(s.z, off); s.w += __shfl_down(s.w, off);
        m.x = fmaxf(m.x, __shfl_down(m.x, off));
        m.y = fmaxf(m.y, __shfl_down(m.y, off));
        m.z = fmaxf(m.z, __shfl_down(m.z, off));
        m.w = fmaxf(m.w, __shfl_down(m.w, off));
    }
    __shared__ float4 ps[4][16], pm[4][16];
    int wave = t >> 6, lane = t & 63;
    if (lane < 16) { ps[wave][lane] = s; pm[wave][lane] = m; }
    __syncthreads();
    if (t < 16) {
        s = ps[0][t]; m = pm[0][t];
#pragma unroll
        for (int g = 1; g < 4; ++g) {
            float4 os = ps[g][t], om = pm[g][t];
            s.x += os.x; s.y += os.y; s.z += os.z; s.w += os.w;
            m.x = fmaxf(m.x, om.x); m.y = fmaxf(m.y, om.y);
            m.z = fmaxf(m.z, om.z); m.w = fmaxf(m.w, om.w);
        }
        const float inv = 1.0f / Cn;
        float4 av = {s.x * inv, s.y * inv, s.z * inv, s.w * inv};
        ((float4*)(avg_sp + b * HWn + seg * 64))[t] = av;
        ((float4*)(max_sp + b * HWn + seg * 64))[t] = m;
    }
}

// ---------------- Kernel 3: fused 7x7 SAME conv + sigmoid + final multiply ----------
// 2048 blocks (8/CU): block = (b, 1 row). Loads the 7-row sp halo into LDS
// (zero-padded), prefetches 4 x-float4 into registers, computes att for its 64 px
// with all 256 threads (4-way ky split), then streams all 256 channels:
// out = x * ch_att * att with float4 stores.
__global__ __launch_bounds__(256) void k_convfinal(const float* __restrict__ x,
                                                   const float* __restrict__ ch_att,
                                                   const float* __restrict__ avg_sp,
                                                   const float* __restrict__ max_sp,
                                                   const float* __restrict__ w_sp,
                                                   float* __restrict__ out) {
    int blk = blockIdx.x;            // Bn*Hn
    int b = blk >> 6;
    int y0 = blk & 63;               // output row
    int t = threadIdx.x;

    __shared__ float ca[Cn];
    __shared__ float wk[98];
    __shared__ float ha[7][64];      // avg_sp halo rows y0-3 .. y0+3 (zero-padded)
    __shared__ float hm[7][64];
    __shared__ float cpart[4][64];   // partial conv sums (ky split)
    __shared__ float att1[64];       // att for the output row

    ca[t] = ch_att[b * Cn + t];
    if (t < 98) wk[t] = w_sp[t];
    const float* ab = avg_sp + b * HWn;
    const float* mb = max_sp + b * HWn;
#pragma unroll
    for (int k = 0; k < 4; ++k) {
        int idx = k * 256 + t;        // 0..1023, first 896 used (2 maps x 7 rows x 64)
        if (idx < 896) {
            int mapi = idx >= 448;
            int j = mapi ? idx - 448 : idx;
            int rr = j >> 6;          // halo row 0..6
            int col = j & 63;
            int y = y0 - 3 + rr;
            float vv = 0.0f;
            if (y >= 0 && y < Hn) vv = (mapi ? mb : ab)[y * Wn + col];
            if (mapi) hm[rr][col] = vv; else ha[rr][col] = vv;
        }
    }

    // prefetch first 4 x-float4 (independent of conv) so HBM latency hides under conv
    int f4 = t & 15;                  // 16 float4 = 64 floats = the row
    int cg = t >> 4;                  // 16 channel groups
    size_t base = ((size_t)b * Cn) * HWn + (size_t)y0 * Wn;
    const float* xb = x + base;
    float* ob = out + base;
    float4 p0 = ((const float4*)(xb + (size_t)(cg) * HWn))[f4];
    float4 p1 = ((const float4*)(xb + (size_t)(16 + cg) * HWn))[f4];
    float4 p2 = ((const float4*)(xb + (size_t)(32 + cg) * HWn))[f4];
    float4 p3 = ((const float4*)(xb + (size_t)(48 + cg) * HWn))[f4];

    __syncthreads();

    {   // conv: all 256 threads; pr splits ky into {0,1},{2,3},{4,5},{6}
        int col = t & 63;
        int pr = t >> 6;
        float acc = 0.0f;
#pragma unroll
        for (int kk = 0; kk < 2; ++kk) {
            int ky = pr * 2 + kk;
            if (ky < 7) {
#pragma unroll
                for (int kx = 0; kx < 7; ++kx) {
                    int xc = col + kx - 3;
                    if (xc < 0 || xc >= Wn) continue;
                    acc += ha[ky][xc] * wk[ky * 7 + kx] + hm[ky][xc] * wk[49 + ky * 7 + kx];
                }
            }
        }
        cpart[pr][col] = acc;
    }
    __syncthreads();
    if (t < 64) att1[t] = sigmoidf_(cpart[0][t] + cpart[1][t] + cpart[2][t] + cpart[3][t]);
    __syncthreads();

    float4 a4 = ((const float4*)att1)[f4];
#pragma unroll
    for (int i = 0; i < 16; ++i) {
        int c = (i << 4) + cg;
        size_t off = (size_t)c * HWn;
        float4 v;
        if (i == 0) v = p0;
        else if (i == 1) v = p1;
        else if (i == 2) v = p2;
        else if (i == 3) v = p3;
        else v = ((const float4*)(xb + off))[f4];
        float sf = ca[c];
        float4 rv;
        rv.x = v.x * sf * a4.x;
        rv.y = v.y * sf * a4.y;
        rv.z = v.z * sf * a4.z;
        rv.w = v.w * sf * a4.w;
        ((float4*)(ob + off))[f4] = rv;
    }
}

extern "C" void kernel_launch(void* const* d_in, const int* in_sizes, int n_in,
                              void* d_out, int out_size, void* d_ws, size_t ws_size,
                              hipStream_t stream) {
    const float* x    = (const float*)d_in[0];   // [32,256,64,64]
    const float* w1   = (const float*)d_in[1];   // [16,256]
    const float* w2   = (const float*)d_in[2];   // [256,16]
    const float* w_sp = (const float*)d_in[3];   // [1,2,7,7]
    float* out = (float*)d_out;

    float* ws = (float*)d_ws;
    float* avg    = ws;                      // B*C
    float* mx     = avg + Bn * Cn;
    float* ch_att = mx + Bn * Cn;
    float* avg_sp = ch_att + Bn * Cn;        // B*HW
    float* max_sp = avg_sp + Bn * HWn;

    k_chanstats<<<Bn * Cn, 256, 0, stream>>>(x, avg, mx);
    k_spstats<<<Bn * 64, 256, 0, stream>>>(x, avg, mx, w1, w2, ch_att, avg_sp, max_sp);
    k_convfinal<<<Bn * Hn, 256, 0, stream>>>(x, ch_att, avg_sp, max_sp, w_sp, out);
}

// Round 5
// 271.961 us; speedup vs baseline: 1.0641x; 1.0201x over previous
//
#include <hip/hip_runtime.h>
#include <math.h>

#define Bn 32
#define Cn 256
#define Hn 64
#define Wn 64
#define HWn 4096
#define CRn 16   // C / R

__device__ __forceinline__ float sigmoidf_(float v) { return 1.0f / (1.0f + __expf(-v)); }

// ---------------- Kernel 1: per-(b,c) mean & max over HW ----------------
__global__ __launch_bounds__(256) void k_chanstats(const float* __restrict__ x,
                                                   float* __restrict__ avg,
                                                   float* __restrict__ mx) {
    int bc = blockIdx.x;                      // 0 .. B*C-1
    const float4* xv = (const float4*)(x + (size_t)bc * HWn);
    int t = threadIdx.x;
    float s = 0.0f, m = -INFINITY;
#pragma unroll
    for (int j = 0; j < 4; ++j) {             // 4096 floats = 1024 float4 / 256 thr
        float4 v = xv[t + j * 256];
        s += v.x + v.y + v.z + v.w;
        m = fmaxf(m, fmaxf(fmaxf(v.x, v.y), fmaxf(v.z, v.w)));
    }
#pragma unroll
    for (int off = 32; off > 0; off >>= 1) {
        s += __shfl_down(s, off);
        m = fmaxf(m, __shfl_down(m, off));
    }
    __shared__ float ss[4], sm[4];
    int wave = t >> 6, lane = t & 63;
    if (lane == 0) { ss[wave] = s; sm[wave] = m; }
    __syncthreads();
    if (t == 0) {
        s = ss[0] + ss[1] + ss[2] + ss[3];
        m = fmaxf(fmaxf(sm[0], sm[1]), fmaxf(sm[2], sm[3]));
        avg[bc] = s * (1.0f / HWn);
        mx[bc]  = m;
    }
}

// ---------------- Kernel 2: MLP (inline, redundant per block) + spatial stats ------
// 2048 blocks. x-prefetch (4 float4) issued BEFORE the MLP phase so the opening
// HBM latency hides under the LDS-staged MLP; then per-(b,hw) mean/max over C of
// x*ch_att for the block's 64-float hw segment. seg==0 blocks store ch_att.
__global__ __launch_bounds__(256) void k_spstats(const float* __restrict__ x,
                                                 const float* __restrict__ avg,
                                                 const float* __restrict__ mx,
                                                 const float* __restrict__ w1,
                                                 const float* __restrict__ w2,
                                                 float* __restrict__ ch_att,
                                                 float* __restrict__ avg_sp,
                                                 float* __restrict__ max_sp) {
    int blk = blockIdx.x;            // Bn*64
    int b = blk >> 6;
    int seg = blk & 63;              // 64-float segment of the HW plane
    int t = threadIdx.x;
    int f4 = t & 15;
    int cg = t >> 4;                 // 16 channel groups

    // ---- issue x prefetch first (independent of MLP) ----
    const float* xb = x + ((size_t)b * Cn) * HWn + seg * 64;
    float4 p0 = ((const float4*)(xb + (size_t)(cg) * HWn))[f4];
    float4 p1 = ((const float4*)(xb + (size_t)(16 + cg) * HWn))[f4];
    float4 p2 = ((const float4*)(xb + (size_t)(32 + cg) * HWn))[f4];
    float4 p3 = ((const float4*)(xb + (size_t)(48 + cg) * HWn))[f4];

    // ---- inline MLP -> satt[256] ----
    __shared__ float sv[2][Cn];
    __shared__ float part[32][8];
    __shared__ float h[32];
    __shared__ float satt[Cn];
    sv[0][t] = avg[b * Cn + t];
    sv[1][t] = mx[b * Cn + t];
    __syncthreads();
    {
        int d  = t & 31;              // dot index: d<16 -> avg-path, else max-path
        int chk = t >> 5;             // chunk 0..7
        int r  = d & 15;
        const float* v = sv[d >> 4];
        const float* wrow = w1 + r * Cn + chk * 32;
        float acc = 0.0f;
#pragma unroll
        for (int c = 0; c < 32; ++c) acc += v[chk * 32 + c] * wrow[c];
        part[d][chk] = acc;
    }
    __syncthreads();
    if (t < 32) {
        float a = 0.0f;
#pragma unroll
        for (int k = 0; k < 8; ++k) a += part[t][k];
        h[t] = fmaxf(a, 0.0f);        // relu
    }
    __syncthreads();
    {
        float a2 = 0.0f;
#pragma unroll
        for (int rr = 0; rr < CRn; ++rr) a2 += (h[rr] + h[CRn + rr]) * w2[t * CRn + rr];
        float catt = sigmoidf_(a2);
        satt[t] = catt;
        if (seg == 0) ch_att[b * Cn + t] = catt;
    }
    __syncthreads();

    // ---- spatial stats over C ----
    float4 s = {0.f, 0.f, 0.f, 0.f};
    float4 m = {-INFINITY, -INFINITY, -INFINITY, -INFINITY};
#pragma unroll
    for (int i = 0; i < 16; ++i) {
        int c = (i << 4) + cg;
        float4 v;
        if (i == 0) v = p0;
        else if (i == 1) v = p1;
        else if (i == 2) v = p2;
        else if (i == 3) v = p3;
        else v = ((const float4*)(xb + (size_t)c * HWn))[f4];
        float a = satt[c];
        v.x *= a; v.y *= a; v.z *= a; v.w *= a;
        s.x += v.x; s.y += v.y; s.z += v.z; s.w += v.w;
        m.x = fmaxf(m.x, v.x); m.y = fmaxf(m.y, v.y);
        m.z = fmaxf(m.z, v.z); m.w = fmaxf(m.w, v.w);
    }
    // reduce across the 4 c-groups within each wave (lane stride 16)
#pragma unroll
    for (int off = 32; off >= 16; off >>= 1) {
        s.x += __shfl_down(s.x, off); s.y += __shfl_down(s.y, off);
        s.z += __shfl_down(s.z, off); s.w += __shfl_down(s.w, off);
        m.x = fmaxf(m.x, __shfl_down(m.x, off));
        m.y = fmaxf(m.y, __shfl_down(m.y, off));
        m.z = fmaxf(m.z, __shfl_down(m.z, off));
        m.w = fmaxf(m.w, __shfl_down(m.w, off));
    }
    __shared__ float4 ps[4][16], pm[4][16];
    int wave = t >> 6, lane = t & 63;
    if (lane < 16) { ps[wave][lane] = s; pm[wave][lane] = m; }
    __syncthreads();
    if (t < 16) {
        s = ps[0][t]; m = pm[0][t];
#pragma unroll
        for (int g = 1; g < 4; ++g) {
            float4 os = ps[g][t], om = pm[g][t];
            s.x += os.x; s.y += os.y; s.z += os.z; s.w += os.w;
            m.x = fmaxf(m.x, om.x); m.y = fmaxf(m.y, om.y);
            m.z = fmaxf(m.z, om.z); m.w = fmaxf(m.w, om.w);
        }
        const float inv = 1.0f / Cn;
        float4 av = {s.x * inv, s.y * inv, s.z * inv, s.w * inv};
        ((float4*)(avg_sp + b * HWn + seg * 64))[t] = av;
        ((float4*)(max_sp + b * HWn + seg * 64))[t] = m;
    }
}

// ---------------- Kernel 3: fused 7x7 SAME conv + sigmoid + final multiply ----------
// 2048 blocks: block = (b, 1 row). 8-deep x register prefetch covers the halo
// load + conv + barriers; conv uses all 256 threads (4-way ky split); then the
// block streams all 256 channels: out = x * ch_att * att with float4 stores.
__global__ __launch_bounds__(256) void k_convfinal(const float* __restrict__ x,
                                                   const float* __restrict__ ch_att,
                                                   const float* __restrict__ avg_sp,
                                                   const float* __restrict__ max_sp,
                                                   const float* __restrict__ w_sp,
                                                   float* __restrict__ out) {
    int blk = blockIdx.x;            // Bn*Hn
    int b = blk >> 6;
    int y0 = blk & 63;               // output row
    int t = threadIdx.x;

    __shared__ float ca[Cn];
    __shared__ float wk[98];
    __shared__ float ha[7][64];      // avg_sp halo rows y0-3 .. y0+3 (zero-padded)
    __shared__ float hm[7][64];
    __shared__ float cpart[4][64];   // partial conv sums (ky split)
    __shared__ float att1[64];       // att for the output row

    // issue the 8-deep x prefetch first (independent of everything below)
    int f4 = t & 15;                  // 16 float4 = 64 floats = the row
    int cg = t >> 4;                  // 16 channel groups
    size_t base = ((size_t)b * Cn) * HWn + (size_t)y0 * Wn;
    const float* xb = x + base;
    float* ob = out + base;
    float4 p0 = ((const float4*)(xb + (size_t)(cg) * HWn))[f4];
    float4 p1 = ((const float4*)(xb + (size_t)(16 + cg) * HWn))[f4];
    float4 p2 = ((const float4*)(xb + (size_t)(32 + cg) * HWn))[f4];
    float4 p3 = ((const float4*)(xb + (size_t)(48 + cg) * HWn))[f4];
    float4 p4 = ((const float4*)(xb + (size_t)(64 + cg) * HWn))[f4];
    float4 p5 = ((const float4*)(xb + (size_t)(80 + cg) * HWn))[f4];
    float4 p6 = ((const float4*)(xb + (size_t)(96 + cg) * HWn))[f4];
    float4 p7 = ((const float4*)(xb + (size_t)(112 + cg) * HWn))[f4];

    ca[t] = ch_att[b * Cn + t];
    if (t < 98) wk[t] = w_sp[t];
    const float* ab = avg_sp + b * HWn;
    const float* mb = max_sp + b * HWn;
#pragma unroll
    for (int k = 0; k < 4; ++k) {
        int idx = k * 256 + t;        // 0..1023, first 896 used (2 maps x 7 rows x 64)
        if (idx < 896) {
            int mapi = idx >= 448;
            int j = mapi ? idx - 448 : idx;
            int rr = j >> 6;          // halo row 0..6
            int col = j & 63;
            int y = y0 - 3 + rr;
            float vv = 0.0f;
            if (y >= 0 && y < Hn) vv = (mapi ? mb : ab)[y * Wn + col];
            if (mapi) hm[rr][col] = vv; else ha[rr][col] = vv;
        }
    }
    __syncthreads();

    {   // conv: all 256 threads; pr splits ky into {0,1},{2,3},{4,5},{6}
        int col = t & 63;
        int pr = t >> 6;
        float acc = 0.0f;
#pragma unroll
        for (int kk = 0; kk < 2; ++kk) {
            int ky = pr * 2 + kk;
            if (ky < 7) {
#pragma unroll
                for (int kx = 0; kx < 7; ++kx) {
                    int xc = col + kx - 3;
                    if (xc < 0 || xc >= Wn) continue;
                    acc += ha[ky][xc] * wk[ky * 7 + kx] + hm[ky][xc] * wk[49 + ky * 7 + kx];
                }
            }
        }
        cpart[pr][col] = acc;
    }
    __syncthreads();
    if (t < 64) att1[t] = sigmoidf_(cpart[0][t] + cpart[1][t] + cpart[2][t] + cpart[3][t]);
    __syncthreads();

    float4 a4 = ((const float4*)att1)[f4];
#pragma unroll
    for (int i = 0; i < 16; ++i) {
        int c = (i << 4) + cg;
        size_t off = (size_t)c * HWn;
        float4 v;
        if (i == 0) v = p0;
        else if (i == 1) v = p1;
        else if (i == 2) v = p2;
        else if (i == 3) v = p3;
        else if (i == 4) v = p4;
        else if (i == 5) v = p5;
        else if (i == 6) v = p6;
        else if (i == 7) v = p7;
        else v = ((const float4*)(xb + off))[f4];
        float sf = ca[c];
        float4 rv;
        rv.x = v.x * sf * a4.x;
        rv.y = v.y * sf * a4.y;
        rv.z = v.z * sf * a4.z;
        rv.w = v.w * sf * a4.w;
        ((float4*)(ob + off))[f4] = rv;
    }
}

extern "C" void kernel_launch(void* const* d_in, const int* in_sizes, int n_in,
                              void* d_out, int out_size, void* d_ws, size_t ws_size,
                              hipStream_t stream) {
    const float* x    = (const float*)d_in[0];   // [32,256,64,64]
    const float* w1   = (const float*)d_in[1];   // [16,256]
    const float* w2   = (const float*)d_in[2];   // [256,16]
    const float* w_sp = (const float*)d_in[3];   // [1,2,7,7]
    float* out = (float*)d_out;

    float* ws = (float*)d_ws;
    float* avg    = ws;                      // B*C
    float* mx     = avg + Bn * Cn;
    float* ch_att = mx + Bn * Cn;
    float* avg_sp = ch_att + Bn * Cn;        // B*HW
    float* max_sp = avg_sp + Bn * HWn;

    k_chanstats<<<Bn * Cn, 256, 0, stream>>>(x, avg, mx);
    k_spstats<<<Bn * 64, 256, 0, stream>>>(x, avg, mx, w1, w2, ch_att, avg_sp, max_sp);
    k_convfinal<<<Bn * Hn, 256, 0, stream>>>(x, ch_att, avg_sp, max_sp, w_sp, out);
}